// Round 1
// baseline (2091.258 us; speedup 1.0000x reference)
//
#include <hip/hip_runtime.h>
#include <math.h>

#define LRELU(x) ((x) > 0.0f ? (x) : 0.01f * (x))

// Tiled gather-conv GEMM: out[b,o,n] = sum_k w[o,k] * g[b,k,n] + bias[o]
// g[b, c*3+j, n] = norm_lrelu(in[b, c, idx[b, 3*(n-1)+j]])  (n>=1), col 0 = 0.
// Fused per-batch sum/sumsq accumulation for the following layernorm.
template <bool NORM_IN>
__global__ __launch_bounds__(256) void conv_gather_kernel(
    const float* __restrict__ in,       // [128, Cin, 1024]
    const int* __restrict__ idx,        // [128, 3069]
    const float* __restrict__ w,        // [O, K]  (K = 3*Cin, matches w_conv layout)
    const float* __restrict__ bias,     // [O]
    const float2* __restrict__ statsIn, // [128] (mean, inv) for input normalization
    float* __restrict__ out,            // [128, O, 1024]
    float* __restrict__ sumsOut,        // [128*2] atomically accumulated (sum, sumsq)
    int Cin, int O, int K)
{
    const int nt  = blockIdx.x;  // n tile (of 16)
    const int ot  = blockIdx.y;  // o tile
    const int b   = blockIdx.z;  // batch
    const int tid = threadIdx.x;

    __shared__ __align__(16) float wt[64][64]; // [k][o]
    __shared__ __align__(16) float gt[64][64]; // [k][n]

    float acc[4][4];
#pragma unroll
    for (int i = 0; i < 4; i++)
#pragma unroll
        for (int j = 0; j < 4; j++) acc[i][j] = 0.0f;

    float meanIn = 0.0f, invIn = 1.0f;
    if (NORM_IN) { float2 s = statsIn[b]; meanIn = s.x; invIn = s.y; }

    const int n0 = nt * 64;
    const int o0 = ot * 64;
    const int tx = tid & 15;  // o quad
    const int ty = tid >> 4;  // n quad

    // Gather source indices: fixed per thread (one output column each).
    const int ng = n0 + (tid & 63);
    int s0 = 0, s1 = 0, s2 = 0;
    if (ng != 0) {
        const int t = ng - 1;
        const int* ip = idx + (size_t)b * 3069 + 3 * t;
        s0 = ip[0]; s1 = ip[1]; s2 = ip[2];
    }
    const float* inb = in + (size_t)b * Cin * 1024;

    const int kcN = K >> 6;
    for (int kc = 0; kc < kcN; ++kc) {
        // --- load w tile: wt[k][o] = w[(o0+o)*K + kc*64 + k] ---
        {
            const int o   = tid >> 2;        // 0..63
            const int kk0 = (tid & 3) * 16;  // 0,16,32,48
            const float* wp = w + (size_t)(o0 + o) * K + kc * 64 + kk0;
#pragma unroll
            for (int i = 0; i < 16; i += 4) {
                float4 v = *(const float4*)(wp + i);
                wt[kk0 + i + 0][o] = v.x;
                wt[kk0 + i + 1][o] = v.y;
                wt[kk0 + i + 2][o] = v.z;
                wt[kk0 + i + 3][o] = v.w;
            }
        }
        // --- load gathered g tile: gt[k][n] ---
        {
            const int n   = tid & 63;
            const int kk0 = (tid >> 6) * 16; // 0,16,32,48
#pragma unroll
            for (int i = 0; i < 16; i++) {
                const int kg = kc * 64 + kk0 + i;
                float v = 0.0f;
                if (ng != 0) {
                    const int c = kg / 3;
                    const int j = kg - c * 3;
                    const int src = (j == 0) ? s0 : ((j == 1) ? s1 : s2);
                    v = inb[(size_t)c * 1024 + src];
                    if (NORM_IN) { v = (v - meanIn) * invIn; v = LRELU(v); }
                }
                gt[kk0 + i][n] = v;
            }
        }
        __syncthreads();
#pragma unroll 8
        for (int k = 0; k < 64; k++) {
            float4 wv = *(const float4*)&wt[k][tx * 4];
            float4 gv = *(const float4*)&gt[k][ty * 4];
            acc[0][0] += wv.x * gv.x; acc[0][1] += wv.x * gv.y;
            acc[0][2] += wv.x * gv.z; acc[0][3] += wv.x * gv.w;
            acc[1][0] += wv.y * gv.x; acc[1][1] += wv.y * gv.y;
            acc[1][2] += wv.y * gv.z; acc[1][3] += wv.y * gv.w;
            acc[2][0] += wv.z * gv.x; acc[2][1] += wv.z * gv.y;
            acc[2][2] += wv.z * gv.z; acc[2][3] += wv.z * gv.w;
            acc[3][0] += wv.w * gv.x; acc[3][1] += wv.w * gv.y;
            acc[3][2] += wv.w * gv.z; acc[3][3] += wv.w * gv.w;
        }
        __syncthreads();
    }

    // --- epilogue: bias, zero column, store, fused stats ---
    float lsum = 0.0f, lsq = 0.0f;
#pragma unroll
    for (int i = 0; i < 4; i++) {
        const int o  = o0 + tx * 4 + i;
        const float bo = bias[o];
#pragma unroll
        for (int j = 0; j < 4; j++) {
            const int n = n0 + ty * 4 + j;
            float v = (n == 0) ? 0.0f : (acc[i][j] + bo);
            out[((size_t)b * O + o) * 1024 + n] = v;
            lsum += v;
            lsq  += v * v;
        }
    }
    // wave (64-lane) reduce, then cross-wave via LDS, one atomic per block
#pragma unroll
    for (int off = 32; off > 0; off >>= 1) {
        lsum += __shfl_down(lsum, off);
        lsq  += __shfl_down(lsq, off);
    }
    __shared__ float red[8];
    const int wave = tid >> 6;
    if ((tid & 63) == 0) { red[wave] = lsum; red[4 + wave] = lsq; }
    __syncthreads();
    if (tid == 0) {
        float s = red[0] + red[1] + red[2] + red[3];
        float q = red[4] + red[5] + red[6] + red[7];
        atomicAdd(&sumsOut[2 * b + 0], s);
        atomicAdd(&sumsOut[2 * b + 1], q);
    }
}

__global__ void finalize_stats(const float* __restrict__ sums,
                               float2* __restrict__ stats, float count)
{
    int b = threadIdx.x;
    if (b < 128) {
        float s = sums[2 * b], q = sums[2 * b + 1];
        float mean = s / count;
        float var  = (q - s * s / count) / (count - 1.0f); // ddof=1
        var = fmaxf(var, 0.0f);
        float inv = 1.0f / (sqrtf(var) + 1e-5f);
        stats[b] = make_float2(mean, inv);
    }
}

// max over n (monotonic => normalize after max), then fc1+lrelu, fc2
__global__ __launch_bounds__(256) void pool_fc_kernel(
    const float* __restrict__ act3,   // [128, 64, 1024] raw conv3 output
    const float2* __restrict__ stats3,
    const float* __restrict__ w_fc1,  // [32, 64]
    const float* __restrict__ b_fc1,  // [32]
    const float* __restrict__ w_fc2,  // [32]
    const float* __restrict__ b_fc2,  // [1]
    float* __restrict__ y)            // [128]
{
    const int b = blockIdx.x;
    const int tid = threadIdx.x;
    const int o = tid & 63, g = tid >> 6;
    const float* p = act3 + ((size_t)b * 64 + o) * 1024 + g * 256;
    float m = -INFINITY;
    for (int i = 0; i < 256; i += 4) {
        float4 v = *(const float4*)(p + i);
        m = fmaxf(m, fmaxf(fmaxf(v.x, v.y), fmaxf(v.z, v.w)));
    }
    __shared__ float red[4][64];
    red[g][o] = m;
    __syncthreads();
    __shared__ float pooled[64];
    __shared__ float hid[32];
    if (tid < 64) {
        float mm = fmaxf(fmaxf(red[0][tid], red[1][tid]),
                         fmaxf(red[2][tid], red[3][tid]));
        float2 s = stats3[b];
        pooled[tid] = (mm - s.x) * s.y;
    }
    __syncthreads();
    if (tid < 32) {
        float h = b_fc1[tid];
#pragma unroll
        for (int c = 0; c < 64; c++) h += pooled[c] * w_fc1[tid * 64 + c];
        hid[tid] = LRELU(h);
    }
    __syncthreads();
    if (tid == 0) {
        float v = b_fc2[0];
#pragma unroll
        for (int c = 0; c < 32; c++) v += hid[c] * w_fc2[c];
        y[b] = v;
    }
}

__global__ void sigmoid_diff(const float* __restrict__ y1,
                             const float* __restrict__ y2,
                             float* __restrict__ out)
{
    int b = threadIdx.x;
    if (b < 128) {
        float d = y1[b] - y2[b];
        out[b] = 1.0f / (1.0f + expf(-d));
    }
}

extern "C" void kernel_launch(void* const* d_in, const int* in_sizes, int n_in,
                              void* d_out, int out_size, void* d_ws, size_t ws_size,
                              hipStream_t stream)
{
    const float* data1 = (const float*)d_in[0];
    const int*   idx1  = (const int*)d_in[1];
    const float* data2 = (const float*)d_in[2];
    const int*   idx2  = (const int*)d_in[3];
    const float* w1 = (const float*)d_in[4];
    const float* b1 = (const float*)d_in[5];
    const float* w2 = (const float*)d_in[6];
    const float* b2 = (const float*)d_in[7];
    const float* w3 = (const float*)d_in[8];
    const float* b3 = (const float*)d_in[9];
    const float* wfc1 = (const float*)d_in[10];
    const float* bfc1 = (const float*)d_in[11];
    const float* wfc2 = (const float*)d_in[12];
    const float* bfc2 = (const float*)d_in[13];

    char* ws = (char*)d_ws;
    float* act1 = (float*)ws;                           // 128*256*1024 f32 = 128 MiB
    float* act2 = (float*)(ws + (size_t)134217728);     // 128*128*1024 f32 = 64 MiB
    float* act3 = act1;                                 // reuse (act1 dead after conv2)
    char* tail  = ws + (size_t)134217728 + 67108864;
    float*  sums  = (float*)tail;                       // 3 layers * 128 * 2 f32
    float2* stats = (float2*)(tail + 4096);             // 3 layers * 128 float2
    float*  yv    = (float*)(tail + 8192);              // 2 towers * 128 f32

    for (int tower = 0; tower < 2; ++tower) {
        const float* data = tower ? data2 : data1;
        const int*   idx  = tower ? idx2 : idx1;
        hipMemsetAsync(sums, 0, 3 * 256 * sizeof(float), stream);

        conv_gather_kernel<false><<<dim3(16, 4, 128), 256, 0, stream>>>(
            data, idx, w1, b1, nullptr, act1, sums + 0, 64, 256, 192);
        finalize_stats<<<1, 128, 0, stream>>>(sums + 0, stats + 0, 256.0f * 1024.0f);

        conv_gather_kernel<true><<<dim3(16, 2, 128), 256, 0, stream>>>(
            act1, idx, w2, b2, stats + 0, act2, sums + 256, 256, 128, 768);
        finalize_stats<<<1, 128, 0, stream>>>(sums + 256, stats + 128, 128.0f * 1024.0f);

        conv_gather_kernel<true><<<dim3(16, 1, 128), 256, 0, stream>>>(
            act2, idx, w3, b3, stats + 128, act3, sums + 512, 128, 64, 384);
        finalize_stats<<<1, 128, 0, stream>>>(sums + 512, stats + 256, 64.0f * 1024.0f);

        pool_fc_kernel<<<128, 256, 0, stream>>>(
            act3, stats + 256, wfc1, bfc1, wfc2, bfc2, yv + tower * 128);
    }
    sigmoid_diff<<<1, 128, 0, stream>>>(yv, yv + 128, (float*)d_out);
}

// Round 2
// 539.535 us; speedup vs baseline: 3.8760x; 3.8760x over previous
//
#include <hip/hip_runtime.h>
#include <math.h>

typedef __attribute__((ext_vector_type(8))) short short8;
typedef __attribute__((ext_vector_type(4))) float f32x4;

#define LRELU(x) ((x) > 0.0f ? (x) : 0.01f * (x))

__device__ __forceinline__ float bf2f(unsigned short h) {
    return __uint_as_float(((unsigned int)h) << 16);
}
__device__ __forceinline__ unsigned short f2bf(float f) {
    unsigned int u = __float_as_uint(f);
    return (unsigned short)((u + 0x7FFFu + ((u >> 16) & 1u)) >> 16);
}

__device__ __forceinline__ void gload_lds16(const void* g, void* l) {
    __builtin_amdgcn_global_load_lds(
        (const __attribute__((address_space(1))) unsigned int*)g,
        (__attribute__((address_space(3))) unsigned int*)l, 16, 0, 0);
}

// w [O][Cin][3] f32  ->  wq [O][3*Cin] bf16 with k' = j*Cin + c
__global__ void prep_weights(const float* __restrict__ w, unsigned short* __restrict__ wq,
                             int O, int Cin)
{
    const int K = 3 * Cin, total = O * K;
    for (int i = blockIdx.x * blockDim.x + threadIdx.x; i < total;
         i += gridDim.x * blockDim.x) {
        int o = i / K, kp = i - o * K;
        int j = kp / Cin, c = kp - j * Cin;
        wq[i] = f2bf(w[(o * Cin + c) * 3 + j]);
    }
}

// data [128][64][1024] f32 -> xT [128][1024][64] bf16
__global__ __launch_bounds__(256) void transpose_in(const float* __restrict__ in,
                                                    unsigned short* __restrict__ xT)
{
    const int b = blockIdx.y, n0 = blockIdx.x * 64;
    const int tid = threadIdx.x;
    __shared__ float tile[64][65];
    const int nn = tid & 63, cw = tid >> 6;
#pragma unroll
    for (int i = 0; i < 16; i++) {
        int c = i * 4 + cw;
        tile[c][nn] = in[((size_t)b * 64 + c) * 1024 + n0 + nn];
    }
    __syncthreads();
    const int n = tid >> 2, cp = (tid & 3) * 16;
    unsigned int pk[8];
#pragma unroll
    for (int i = 0; i < 8; i++) {
        unsigned short lo = f2bf(tile[cp + 2 * i][n]);
        unsigned short hi = f2bf(tile[cp + 2 * i + 1][n]);
        pk[i] = (unsigned int)lo | ((unsigned int)hi << 16);
    }
    unsigned short* dst = xT + ((size_t)b * 1024 + n0 + n) * 64 + cp;
    uint4 v0 = {pk[0], pk[1], pk[2], pk[3]};
    uint4 v1 = {pk[4], pk[5], pk[6], pk[7]};
    *(uint4*)dst = v0;
    *(uint4*)(dst + 8) = v1;
}

// MFMA gather-conv: out[b][n][o] = sum_k wq[o][k'] * xT[b][src_j(n)][c] (+bias, col0=0)
// LDS rows = 128B, block-swizzled (phys = logical ^ (row&7)) for conflict-free b128 reads.
template <int BM>
__global__ __launch_bounds__(256) void conv_mfma(
    const unsigned short* __restrict__ xT,   // [128][1024][Cin] bf16
    const int* __restrict__ idx,             // [128][3069]
    const unsigned short* __restrict__ wq,   // [O][K] bf16 (k'=j*Cin+c)
    const float* __restrict__ bias,          // [O] f32
    unsigned short* __restrict__ out,        // [128][1024][O] bf16
    float* __restrict__ sums,                // [128][2] accum
    int Cin, int cinShift, int O, int K)
{
    constexpr int WM = BM / 2, MT = WM / 16;
    const int nt0 = blockIdx.x << 7;
    const int o0  = blockIdx.y * BM;
    const int b   = blockIdx.z;
    const int tid = threadIdx.x;
    const int lane = tid & 63, wave = tid >> 6;
    const int wo = wave & 1, wn = wave >> 1;
    const int quad = lane >> 4, l15 = lane & 15;
    const int rl = (lane >> 3) & 7, blkid = lane & 7;
    const int swz = blkid ^ rl;   // logical 16B-block this lane stages

    __shared__ __align__(16) unsigned short wt[BM * 64];
    __shared__ __align__(16) unsigned short gt[128 * 64];
    __shared__ float red[8];

    f32x4 acc[MT][4];
#pragma unroll
    for (int i = 0; i < MT; i++)
#pragma unroll
        for (int t = 0; t < 4; t++) acc[i][t] = (f32x4){0.f, 0.f, 0.f, 0.f};

    const unsigned short* xTb = xT + (((size_t)b) << 10) * (size_t)Cin;
    const int* idxb = idx + b * 3069;
    const int* ip[4];
#pragma unroll
    for (int p = 0; p < 4; p++) {
        int n = nt0 + p * 32 + wave * 8 + rl;
        int t = (n == 0) ? 0 : (n - 1);
        ip[p] = idxb + 3 * t;
    }

    const int nChunks = K >> 6;
    for (int kc = 0; kc < nChunks; ++kc) {
        const int k64 = kc << 6;
        const int j  = k64 >> cinShift;
        const int c0 = k64 & (Cin - 1);
#pragma unroll
        for (int p = 0; p < BM / 32; p++) {
            const int r0 = p * 32 + wave * 8;
            const int orow = o0 + r0 + rl;
            gload_lds16(wq + (size_t)orow * K + k64 + swz * 8, &wt[r0 * 64 + lane * 8]);
        }
#pragma unroll
        for (int p = 0; p < 4; p++) {
            const int s = ip[p][j];
            gload_lds16(xTb + (size_t)s * Cin + c0 + swz * 8,
                        &gt[(p * 32 + wave * 8) * 64 + lane * 8]);
        }
        __syncthreads();
#pragma unroll
        for (int st = 0; st < 2; ++st) {
            short8 af[MT], bfv[4];
            const int qb = st * 4 + quad;
#pragma unroll
            for (int i = 0; i < MT; i++) {
                const int orow = wo * WM + i * 16 + l15;
                af[i] = *(const short8*)&wt[orow * 64 + ((qb ^ blkid) << 3)];
            }
#pragma unroll
            for (int t = 0; t < 4; t++) {
                const int nrow = wn * 64 + t * 16 + l15;
                bfv[t] = *(const short8*)&gt[nrow * 64 + ((qb ^ blkid) << 3)];
            }
#pragma unroll
            for (int i = 0; i < MT; i++)
#pragma unroll
                for (int t = 0; t < 4; t++)
                    acc[i][t] = __builtin_amdgcn_mfma_f32_16x16x32_bf16(
                        af[i], bfv[t], acc[i][t], 0, 0, 0);
        }
        __syncthreads();
    }

    // epilogue: bias, zero col 0, bf16 store, fused stats
    float lsum = 0.f, lsq = 0.f;
#pragma unroll
    for (int i = 0; i < MT; i++) {
        const int ob = o0 + wo * WM + i * 16 + quad * 4;
        const float4 bv = *(const float4*)(bias + ob);
#pragma unroll
        for (int t = 0; t < 4; t++) {
            const int n = nt0 + wn * 64 + t * 16 + l15;
            float v0 = acc[i][t][0] + bv.x;
            float v1 = acc[i][t][1] + bv.y;
            float v2 = acc[i][t][2] + bv.z;
            float v3 = acc[i][t][3] + bv.w;
            if (n == 0) { v0 = v1 = v2 = v3 = 0.f; }
            lsum += v0 + v1 + v2 + v3;
            lsq  += v0 * v0 + v1 * v1 + v2 * v2 + v3 * v3;
            ushort4 pk;
            pk.x = f2bf(v0); pk.y = f2bf(v1); pk.z = f2bf(v2); pk.w = f2bf(v3);
            *(ushort4*)&out[((size_t)b * 1024 + n) * O + ob] = pk;
        }
    }
#pragma unroll
    for (int off = 32; off > 0; off >>= 1) {
        lsum += __shfl_down(lsum, off);
        lsq  += __shfl_down(lsq, off);
    }
    if (lane == 0) { red[wave] = lsum; red[4 + wave] = lsq; }
    __syncthreads();
    if (tid == 0) {
        atomicAdd(&sums[2 * b + 0], red[0] + red[1] + red[2] + red[3]);
        atomicAdd(&sums[2 * b + 1], red[4] + red[5] + red[6] + red[7]);
    }
}

__global__ void finalize_stats(const float* __restrict__ sums,
                               float2* __restrict__ stats, float count)
{
    int b = threadIdx.x;
    if (b < 128) {
        float s = sums[2 * b], q = sums[2 * b + 1];
        float mean = s / count;
        float var = (q - s * s / count) / (count - 1.0f);  // ddof=1
        var = fmaxf(var, 0.0f);
        stats[b] = make_float2(mean, 1.0f / (sqrtf(var) + 1e-5f));
    }
}

// in-place: act = lrelu((act - mean) * inv), act bf16 [128][1024][C]
__global__ __launch_bounds__(256) void normalize_act(unsigned short* __restrict__ act,
                                                     const float2* __restrict__ stats, int C)
{
    const int b = blockIdx.y;
    const float2 s = stats[b];
    const float a = s.y, c2 = -s.x * s.y;
    size_t off = (((size_t)b << 10) * C) + ((size_t)blockIdx.x * 2048) + (size_t)threadIdx.x * 8;
    uint4* p = (uint4*)(act + off);
    uint4 v = *p;
    unsigned int w[4] = {v.x, v.y, v.z, v.w};
#pragma unroll
    for (int i = 0; i < 4; i++) {
        float lo = bf2f((unsigned short)(w[i] & 0xFFFFu));
        float hi = bf2f((unsigned short)(w[i] >> 16));
        lo = fmaf(lo, a, c2); lo = fmaxf(lo, 0.01f * lo);
        hi = fmaf(hi, a, c2); hi = fmaxf(hi, 0.01f * hi);
        w[i] = (unsigned int)f2bf(lo) | ((unsigned int)f2bf(hi) << 16);
    }
    uint4 r = {w[0], w[1], w[2], w[3]};
    *p = r;
}

// max over n (normalize pooled scalar: monotonic), fc1+lrelu, fc2
__global__ __launch_bounds__(256) void pool_fc(
    const unsigned short* __restrict__ act3,  // [128][1024][64] bf16
    const float2* __restrict__ stats3,
    const float* __restrict__ w_fc1, const float* __restrict__ b_fc1,
    const float* __restrict__ w_fc2, const float* __restrict__ b_fc2,
    float* __restrict__ y)
{
    const int b = blockIdx.x, tid = threadIdx.x;
    const int o = tid & 63, g = tid >> 6;
    const unsigned short* p = act3 + ((size_t)b * 1024 + g * 256) * 64 + o;
    float m = -1e30f;
#pragma unroll 8
    for (int i = 0; i < 256; i++) m = fmaxf(m, bf2f(p[(size_t)i * 64]));
    __shared__ float red[4][64];
    red[g][o] = m;
    __syncthreads();
    __shared__ float pooled[64];
    __shared__ float hid[32];
    if (tid < 64) {
        float mm = fmaxf(fmaxf(red[0][tid], red[1][tid]),
                         fmaxf(red[2][tid], red[3][tid]));
        float2 s = stats3[b];
        pooled[tid] = (mm - s.x) * s.y;
    }
    __syncthreads();
    if (tid < 32) {
        float h = b_fc1[tid];
#pragma unroll
        for (int c = 0; c < 64; c++) h += pooled[c] * w_fc1[tid * 64 + c];
        hid[tid] = LRELU(h);
    }
    __syncthreads();
    if (tid == 0) {
        float v = b_fc2[0];
#pragma unroll
        for (int c = 0; c < 32; c++) v += hid[c] * w_fc2[c];
        y[b] = v;
    }
}

__global__ void sigmoid_diff(const float* __restrict__ y1,
                             const float* __restrict__ y2,
                             float* __restrict__ out)
{
    int b = threadIdx.x;
    if (b < 128) out[b] = 1.0f / (1.0f + expf(-(y1[b] - y2[b])));
}

extern "C" void kernel_launch(void* const* d_in, const int* in_sizes, int n_in,
                              void* d_out, int out_size, void* d_ws, size_t ws_size,
                              hipStream_t stream)
{
    const float* data1 = (const float*)d_in[0];
    const int*   idx1  = (const int*)d_in[1];
    const float* data2 = (const float*)d_in[2];
    const int*   idx2  = (const int*)d_in[3];
    const float* w1 = (const float*)d_in[4];
    const float* b1 = (const float*)d_in[5];
    const float* w2 = (const float*)d_in[6];
    const float* b2 = (const float*)d_in[7];
    const float* w3 = (const float*)d_in[8];
    const float* b3 = (const float*)d_in[9];
    const float* wfc1 = (const float*)d_in[10];
    const float* bfc1 = (const float*)d_in[11];
    const float* wfc2 = (const float*)d_in[12];
    const float* bfc2 = (const float*)d_in[13];

    const size_t MB = 1024 * 1024;
    char* ws = (char*)d_ws;
    unsigned short* xT = (unsigned short*)ws;                    // 16 MB
    unsigned short* a1 = (unsigned short*)(ws + 16 * MB);        // 64 MB
    unsigned short* a2 = (unsigned short*)(ws + 80 * MB);        // 32 MB
    unsigned short* a3 = (unsigned short*)(ws + 112 * MB);       // 16 MB
    unsigned short* wq1 = (unsigned short*)(ws + 128 * MB);          // 96 KB
    unsigned short* wq2 = (unsigned short*)(ws + 128 * MB + 512 * 1024); // 192 KB
    unsigned short* wq3 = (unsigned short*)(ws + 129 * MB);          // 48 KB
    float*  sums  = (float*)(ws + 130 * MB);                     // 3*128*2 f32
    float2* stats = (float2*)(ws + 130 * MB + 4096);             // 3*128 float2
    float*  yv    = (float*)(ws + 130 * MB + 8192);              // 2*128 f32

    prep_weights<<<96, 256, 0, stream>>>(w1, wq1, 256, 64);
    prep_weights<<<96, 256, 0, stream>>>(w2, wq2, 128, 256);
    prep_weights<<<96, 256, 0, stream>>>(w3, wq3, 64, 128);

    for (int tower = 0; tower < 2; ++tower) {
        const float* data = tower ? data2 : data1;
        const int*   idx  = tower ? idx2 : idx1;
        hipMemsetAsync(sums, 0, 3 * 256 * sizeof(float), stream);

        transpose_in<<<dim3(16, 128), 256, 0, stream>>>(data, xT);

        conv_mfma<128><<<dim3(8, 2, 128), 256, 0, stream>>>(
            xT, idx, wq1, b1, a1, sums + 0, 64, 6, 256, 192);
        finalize_stats<<<1, 128, 0, stream>>>(sums + 0, stats + 0, 256.0f * 1024.0f);
        normalize_act<<<dim3(128, 128), 256, 0, stream>>>(a1, stats + 0, 256);

        conv_mfma<128><<<dim3(8, 1, 128), 256, 0, stream>>>(
            a1, idx, wq2, b2, a2, sums + 256, 256, 8, 128, 768);
        finalize_stats<<<1, 128, 0, stream>>>(sums + 256, stats + 128, 128.0f * 1024.0f);
        normalize_act<<<dim3(64, 128), 256, 0, stream>>>(a2, stats + 128, 128);

        conv_mfma<64><<<dim3(8, 1, 128), 256, 0, stream>>>(
            a2, idx, wq3, b3, a3, sums + 512, 128, 7, 64, 384);
        finalize_stats<<<1, 128, 0, stream>>>(sums + 512, stats + 256, 64.0f * 1024.0f);

        pool_fc<<<128, 256, 0, stream>>>(a3, stats + 256, wfc1, bfc1, wfc2, bfc2,
                                         yv + tower * 128);
    }
    sigmoid_diff<<<1, 128, 0, stream>>>(yv, yv + 128, (float*)d_out);
}

// Round 3
// 442.974 us; speedup vs baseline: 4.7209x; 1.2180x over previous
//
#include <hip/hip_runtime.h>
#include <math.h>

typedef __attribute__((ext_vector_type(8))) short short8;
typedef __attribute__((ext_vector_type(4))) float f32x4;

#define LRELU(x) ((x) > 0.0f ? (x) : 0.01f * (x))

__device__ __forceinline__ float bf2f(unsigned short h) {
    return __uint_as_float(((unsigned int)h) << 16);
}
__device__ __forceinline__ unsigned short f2bf(float f) {
    unsigned int u = __float_as_uint(f);
    return (unsigned short)((u + 0x7FFFu + ((u >> 16) & 1u)) >> 16);
}
__device__ __forceinline__ void gload_lds16(const void* g, void* l) {
    __builtin_amdgcn_global_load_lds(
        (const __attribute__((address_space(1))) unsigned int*)g,
        (__attribute__((address_space(3))) unsigned int*)l, 16, 0, 0);
}
__device__ __forceinline__ float2 stats_from(const float* sums, int b, float count) {
    float s = sums[2 * b], q = sums[2 * b + 1];
    float mean = s / count;
    float var = (q - s * s / count) / (count - 1.0f);  // ddof=1
    var = fmaxf(var, 0.0f);
    return make_float2(mean, 1.0f / (sqrtf(var) + 1e-5f));
}

// w [O][Cin][3] f32  ->  wq [O][3*Cin] bf16 with k' = j*Cin + c
__global__ void prep_weights(const float* __restrict__ w, unsigned short* __restrict__ wq,
                             int O, int Cin)
{
    const int K = 3 * Cin, total = O * K;
    for (int i = blockIdx.x * blockDim.x + threadIdx.x; i < total;
         i += gridDim.x * blockDim.x) {
        int o = i / K, kp = i - o * K;
        int j = kp / Cin, c = kp - j * Cin;
        wq[i] = f2bf(w[(o * Cin + c) * 3 + j]);
    }
}

// data [128][64][1024] f32 -> xT [nB][1024][64] bf16 (tower select on b>=128)
__global__ __launch_bounds__(256) void transpose_in(const float* __restrict__ inA,
                                                    const float* __restrict__ inB,
                                                    unsigned short* __restrict__ xT)
{
    const int b = blockIdx.y, n0 = blockIdx.x * 64;
    const float* in = (b >= 128 ? inB : inA) + ((size_t)(b & 127) * 64) * 1024;
    const int tid = threadIdx.x;
    __shared__ float tile[64][65];
    const int nn = tid & 63, cw = tid >> 6;
#pragma unroll
    for (int i = 0; i < 16; i++) {
        int c = i * 4 + cw;
        tile[c][nn] = in[(size_t)c * 1024 + n0 + nn];
    }
    __syncthreads();
    const int n = tid >> 2, cp = (tid & 3) * 16;
    unsigned int pk[8];
#pragma unroll
    for (int i = 0; i < 8; i++) {
        unsigned short lo = f2bf(tile[cp + 2 * i][n]);
        unsigned short hi = f2bf(tile[cp + 2 * i + 1][n]);
        pk[i] = (unsigned int)lo | ((unsigned int)hi << 16);
    }
    unsigned short* dst = xT + ((size_t)b * 1024 + n0 + n) * 64 + cp;
    uint4 v0 = {pk[0], pk[1], pk[2], pk[3]};
    uint4 v1 = {pk[4], pk[5], pk[6], pk[7]};
    *(uint4*)dst = v0;
    *(uint4*)(dst + 8) = v1;
}

// MFMA gather-conv. blockIdx.x = batch (multiple of 8 wide => XCD-pinned L2 slab),
// blockIdx.y = o-tile, blockIdx.z = n-tile.
template <int BM>
__global__ __launch_bounds__(256) void conv_mfma(
    const unsigned short* __restrict__ xT,   // [nB][1024][Cin] bf16
    const int* __restrict__ idxA,            // [128][3069]
    const int* __restrict__ idxB,            // tower-1 indices (== idxA in fallback)
    const unsigned short* __restrict__ wq,   // [O][K] bf16 (k'=j*Cin+c)
    const float* __restrict__ bias,          // [O] f32
    unsigned short* __restrict__ out,        // [nB][1024][O] bf16
    float* __restrict__ sums,                // [nB][2] accum
    int Cin, int cinShift, int O, int K)
{
    constexpr int WM = BM / 2, MT = WM / 16;
    const int b   = blockIdx.x;
    const int o0  = blockIdx.y * BM;
    const int nt0 = blockIdx.z << 7;
    const int tid = threadIdx.x;
    const int lane = tid & 63, wave = tid >> 6;
    const int wo = wave & 1, wn = wave >> 1;
    const int quad = lane >> 4, l15 = lane & 15;
    const int rl = (lane >> 3) & 7, blkid = lane & 7;
    const int swz = blkid ^ rl;   // logical 16B-block this lane stages

    __shared__ __align__(16) unsigned short wt[BM * 64];
    __shared__ __align__(16) unsigned short gt[128 * 64];

    f32x4 acc[MT][4];
#pragma unroll
    for (int i = 0; i < MT; i++)
#pragma unroll
        for (int t = 0; t < 4; t++) acc[i][t] = (f32x4){0.f, 0.f, 0.f, 0.f};

    const unsigned short* xTb = xT + (((size_t)b) << 10) * (size_t)Cin;
    const int* idxb = (b >= 128 ? idxB : idxA) + (size_t)(b & 127) * 3069;
    const int* ip[4];
#pragma unroll
    for (int p = 0; p < 4; p++) {
        int n = nt0 + p * 32 + wave * 8 + rl;
        int t = (n == 0) ? 0 : (n - 1);
        ip[p] = idxb + 3 * t;
    }

    const int nChunks = K >> 6;
    for (int kc = 0; kc < nChunks; ++kc) {
        const int k64 = kc << 6;
        const int j  = k64 >> cinShift;
        const int c0 = k64 & (Cin - 1);
#pragma unroll
        for (int p = 0; p < BM / 32; p++) {
            const int r0 = p * 32 + wave * 8;
            const int orow = o0 + r0 + rl;
            gload_lds16(wq + (size_t)orow * K + k64 + swz * 8, &wt[r0 * 64 + lane * 8]);
        }
#pragma unroll
        for (int p = 0; p < 4; p++) {
            const int s = ip[p][j];
            gload_lds16(xTb + (size_t)s * Cin + c0 + swz * 8,
                        &gt[(p * 32 + wave * 8) * 64 + lane * 8]);
        }
        __syncthreads();
#pragma unroll
        for (int st = 0; st < 2; ++st) {
            short8 af[MT], bfv[4];
            const int qb = st * 4 + quad;
#pragma unroll
            for (int i = 0; i < MT; i++) {
                const int orow = wo * WM + i * 16 + l15;
                af[i] = *(const short8*)&wt[orow * 64 + ((qb ^ blkid) << 3)];
            }
#pragma unroll
            for (int t = 0; t < 4; t++) {
                const int nrow = wn * 64 + t * 16 + l15;
                bfv[t] = *(const short8*)&gt[nrow * 64 + ((qb ^ blkid) << 3)];
            }
#pragma unroll
            for (int i = 0; i < MT; i++)
#pragma unroll
                for (int t = 0; t < 4; t++)
                    acc[i][t] = __builtin_amdgcn_mfma_f32_16x16x32_bf16(
                        af[i], bfv[t], acc[i][t], 0, 0, 0);
        }
        __syncthreads();
    }

    // epilogue: bias, zero col 0, bf16 store, fused stats
    float lsum = 0.f, lsq = 0.f;
#pragma unroll
    for (int i = 0; i < MT; i++) {
        const int ob = o0 + wo * WM + i * 16 + quad * 4;
        const float4 bv = *(const float4*)(bias + ob);
#pragma unroll
        for (int t = 0; t < 4; t++) {
            const int n = nt0 + wn * 64 + t * 16 + l15;
            float v0 = acc[i][t][0] + bv.x;
            float v1 = acc[i][t][1] + bv.y;
            float v2 = acc[i][t][2] + bv.z;
            float v3 = acc[i][t][3] + bv.w;
            if (n == 0) { v0 = v1 = v2 = v3 = 0.f; }
            lsum += v0 + v1 + v2 + v3;
            lsq  += v0 * v0 + v1 * v1 + v2 * v2 + v3 * v3;
            ushort4 pk;
            pk.x = f2bf(v0); pk.y = f2bf(v1); pk.z = f2bf(v2); pk.w = f2bf(v3);
            *(ushort4*)&out[((size_t)b * 1024 + n) * O + ob] = pk;
        }
    }
#pragma unroll
    for (int off = 32; off > 0; off >>= 1) {
        lsum += __shfl_down(lsum, off);
        lsq  += __shfl_down(lsq, off);
    }
    float* red = (float*)wt;  // wt dead after K-loop; stays under 32 KB LDS
    if (lane == 0) { red[wave] = lsum; red[4 + wave] = lsq; }
    __syncthreads();
    if (tid == 0) {
        atomicAdd(&sums[2 * b + 0], red[0] + red[1] + red[2] + red[3]);
        atomicAdd(&sums[2 * b + 1], red[4] + red[5] + red[6] + red[7]);
    }
}

// in-place: act = lrelu((act - mean) * inv); stats recomputed from sums per block
__global__ __launch_bounds__(256) void normalize_act(unsigned short* __restrict__ act,
                                                     const float* __restrict__ sums,
                                                     float count, int C)
{
    const int b = blockIdx.y;
    const float2 s = stats_from(sums, b, count);
    const float a = s.y, c2 = -s.x * s.y;
    size_t off = (((size_t)b << 10) * C) + ((size_t)blockIdx.x * 2048) + (size_t)threadIdx.x * 8;
    uint4* p = (uint4*)(act + off);
    uint4 v = *p;
    unsigned int w[4] = {v.x, v.y, v.z, v.w};
#pragma unroll
    for (int i = 0; i < 4; i++) {
        float lo = bf2f((unsigned short)(w[i] & 0xFFFFu));
        float hi = bf2f((unsigned short)(w[i] >> 16));
        lo = fmaf(lo, a, c2); lo = fmaxf(lo, 0.01f * lo);
        hi = fmaf(hi, a, c2); hi = fmaxf(hi, 0.01f * hi);
        w[i] = (unsigned int)f2bf(lo) | ((unsigned int)f2bf(hi) << 16);
    }
    uint4 r = {w[0], w[1], w[2], w[3]};
    *p = r;
}

// max over n (normalize pooled scalar: monotonic), fc1+lrelu, fc2
__global__ __launch_bounds__(256) void pool_fc(
    const unsigned short* __restrict__ act3,  // [nB][1024][64] bf16
    const float* __restrict__ sums3, float count,
    const float* __restrict__ w_fc1, const float* __restrict__ b_fc1,
    const float* __restrict__ w_fc2, const float* __restrict__ b_fc2,
    float* __restrict__ y)
{
    const int b = blockIdx.x, tid = threadIdx.x;
    const int o = tid & 63, g = tid >> 6;
    const unsigned short* p = act3 + ((size_t)b * 1024 + g * 256) * 64 + o;
    float m = -1e30f;
#pragma unroll 8
    for (int i = 0; i < 256; i++) m = fmaxf(m, bf2f(p[(size_t)i * 64]));
    __shared__ float red[4][64];
    red[g][o] = m;
    __syncthreads();
    __shared__ float pooled[64];
    __shared__ float hid[32];
    if (tid < 64) {
        float mm = fmaxf(fmaxf(red[0][tid], red[1][tid]),
                         fmaxf(red[2][tid], red[3][tid]));
        float2 s = stats_from(sums3, b, count);
        pooled[tid] = (mm - s.x) * s.y;
    }
    __syncthreads();
    if (tid < 32) {
        float h = b_fc1[tid];
#pragma unroll
        for (int c = 0; c < 64; c++) h += pooled[c] * w_fc1[tid * 64 + c];
        hid[tid] = LRELU(h);
    }
    __syncthreads();
    if (tid == 0) {
        float v = b_fc2[0];
#pragma unroll
        for (int c = 0; c < 32; c++) v += hid[c] * w_fc2[c];
        y[b] = v;
    }
}

__global__ void sigmoid_diff(const float* __restrict__ y1,
                             const float* __restrict__ y2,
                             float* __restrict__ out)
{
    int b = threadIdx.x;
    if (b < 128) out[b] = 1.0f / (1.0f + expf(-(y1[b] - y2[b])));
}

extern "C" void kernel_launch(void* const* d_in, const int* in_sizes, int n_in,
                              void* d_out, int out_size, void* d_ws, size_t ws_size,
                              hipStream_t stream)
{
    const float* data1 = (const float*)d_in[0];
    const int*   idx1  = (const int*)d_in[1];
    const float* data2 = (const float*)d_in[2];
    const int*   idx2  = (const int*)d_in[3];
    const float* w1 = (const float*)d_in[4];
    const float* b1 = (const float*)d_in[5];
    const float* w2 = (const float*)d_in[6];
    const float* b2 = (const float*)d_in[7];
    const float* w3 = (const float*)d_in[8];
    const float* b3 = (const float*)d_in[9];
    const float* wfc1 = (const float*)d_in[10];
    const float* bfc1 = (const float*)d_in[11];
    const float* wfc2 = (const float*)d_in[12];
    const float* bfc2 = (const float*)d_in[13];

    const size_t MB = 1024 * 1024;
    const bool merged = ws_size >= 225 * MB;  // ws_size is constant across calls
    const int nB = merged ? 256 : 128;
    const size_t szXT = (size_t)nB * 1024 * 64 * 2;    // also a3
    const size_t szA1 = (size_t)nB * 1024 * 256 * 2;
    const size_t szA2 = (size_t)nB * 1024 * 128 * 2;

    char* ws = (char*)d_ws;
    unsigned short* xT = (unsigned short*)ws;                 // aliases a3
    unsigned short* a1 = (unsigned short*)(ws + szXT);
    unsigned short* a2 = (unsigned short*)(ws + szXT + szA1);
    unsigned short* a3 = xT;
    char* tail = ws + szXT + szA1 + szA2;
    unsigned short* wq1 = (unsigned short*)tail;              // 96 KB
    unsigned short* wq2 = (unsigned short*)(tail + 128 * 1024);  // 192 KB
    unsigned short* wq3 = (unsigned short*)(tail + 384 * 1024);  // 48 KB
    float* sums  = (float*)(tail + 448 * 1024);               // 3 * 512 f32
    float* yv    = (float*)(tail + 456 * 1024);               // 256 f32

    prep_weights<<<96, 256, 0, stream>>>(w1, wq1, 256, 64);
    prep_weights<<<96, 256, 0, stream>>>(w2, wq2, 128, 256);
    prep_weights<<<96, 256, 0, stream>>>(w3, wq3, 64, 128);

    const int nIter = merged ? 1 : 2;
    for (int t = 0; t < nIter; ++t) {
        const float* dA = (merged || t == 0) ? data1 : data2;
        const float* dB = merged ? data2 : dA;
        const int* iA = (merged || t == 0) ? idx1 : idx2;
        const int* iB = merged ? idx2 : iA;

        hipMemsetAsync(sums, 0, 3 * 512 * sizeof(float), stream);

        transpose_in<<<dim3(16, nB), 256, 0, stream>>>(dA, dB, xT);

        conv_mfma<128><<<dim3(nB, 2, 8), 256, 0, stream>>>(
            xT, iA, iB, wq1, b1, a1, sums + 0, 64, 6, 256, 192);
        normalize_act<<<dim3(128, nB), 256, 0, stream>>>(a1, sums + 0,
                                                         256.0f * 1024.0f, 256);

        conv_mfma<128><<<dim3(nB, 1, 8), 256, 0, stream>>>(
            a1, iA, iB, wq2, b2, a2, sums + 512, 256, 8, 128, 768);
        normalize_act<<<dim3(64, nB), 256, 0, stream>>>(a2, sums + 512,
                                                        128.0f * 1024.0f, 128);

        conv_mfma<64><<<dim3(nB, 1, 8), 256, 0, stream>>>(
            a2, iA, iB, wq3, b3, a3, sums + 1024, 128, 7, 64, 384);

        pool_fc<<<nB, 256, 0, stream>>>(a3, sums + 1024, 64.0f * 1024.0f,
                                        wfc1, bfc1, wfc2, bfc2,
                                        yv + (merged ? 0 : t * 128));
    }
    sigmoid_diff<<<1, 128, 0, stream>>>(yv, yv + 128, (float*)d_out);
}